// Round 2
// 497.409 us; speedup vs baseline: 1.0261x; 1.0261x over previous
//
#include <hip/hip_runtime.h>
#include <cstddef>
#include <cmath>

// Problem constants (from reference)
#define BATCH 2
#define CIN 3
#define H 48
#define KS 5
#define KN 16
#define OW 44               // H - KS + 1
#define P 1936              // OW*OW patches
#define F 75                // CIN*KS*KS
#define MU_OUT_SIZE (BATCH*KN*P)   // 61952

// Native clang vector type — __builtin_nontemporal_store requires a vector of
// scalar types, not HIP's float4 class.
typedef float floatx4 __attribute__((ext_vector_type(4)));

// ---------------------------------------------------------------------------
// Kernel 1: build xmT[b][f][q]  (q contiguous so sigma kernel q-loads coalesce)
// xmT[b][f][q] = mu_in[b][c][qy+kh][qx+kw],  f=(c,kh,kw), q=qy*44+qx
// Plain (cached) stores: xmT is re-read 968x by sigma blocks — we WANT it in L2.
// ---------------------------------------------------------------------------
__global__ void build_patches(const float* __restrict__ mu_in,
                              float* __restrict__ xmT) {
    int idx = blockIdx.x * 256 + threadIdx.x;
    if (idx >= BATCH * F * P) return;
    int q = idx % P;
    int f = (idx / P) % F;
    int b = idx / (F * P);
    int c  = f / (KS * KS);
    int r  = f % (KS * KS);
    int kh = r / KS, kw = r % KS;
    int qy = q / OW, qx = q % OW;
    xmT[idx] = mu_in[((b * CIN + c) * H + (qy + kh)) * H + (qx + kw)];
}

// ---------------------------------------------------------------------------
// Kernel 2: mean path — direct 5x5 valid conv, weights in LDS
// out[b][n][p] ,  p = py*44+px
// Output is write-once (never re-read on device) -> nontemporal store.
// ---------------------------------------------------------------------------
__global__ void conv_mu(const float* __restrict__ mu_in,
                        const float* __restrict__ w_mu,
                        float* __restrict__ out) {
    __shared__ float wsh[KN * F];
    for (int i = threadIdx.x; i < KN * F; i += 256) wsh[i] = w_mu[i];
    __syncthreads();
    int idx = blockIdx.x * 256 + threadIdx.x;
    if (idx >= MU_OUT_SIZE) return;
    int p = idx % P;
    int n = (idx / P) % KN;
    int b = idx / (P * KN);
    int py = p / OW, px = p % OW;
    const float* img = mu_in + b * CIN * H * H;
    const float* w   = wsh + n * F;
    float acc = 0.f;
#pragma unroll
    for (int c = 0; c < CIN; c++)
#pragma unroll
        for (int kh = 0; kh < KS; kh++)
#pragma unroll
            for (int kw = 0; kw < KS; kw++)
                acc += img[(c * H + py + kh) * H + (px + kw)] *
                       w[c * KS * KS + kh * KS + kw];
    __builtin_nontemporal_store(acc, out + idx);
}

// ---------------------------------------------------------------------------
// Kernel 3: sigma[b][n][p][q] = dot_f(xm[p], xm[q]) * softplus(w_sigma[n])
// Block: 256 threads = one (b, 8-p tile, 1024-q tile).
// Each thread owns 4 consecutive q (float4), accumulates acc[8][4],
// then writes 8p x 16n float4 stores (all coalesced dwordx4, nontemporal).
//
// The 480 MB output stream is write-once: a cached store path pushes it
// through the 32 MB aggregate L2, evicting the 1.1 MB xmT panel that every
// block re-reads (290 MB of xq re-reads total). Evicted xq loads become
// ~900-cycle dependent HBM misses in the f-loop that ~3.8 waves/SIMD cannot
// hide. Nontemporal (nt) stores keep the write stream out of L2 -> xmT stays
// resident -> all xq loads are L2 hits.
// ---------------------------------------------------------------------------
#define TP 8
#define TQ 1024
#define NQB 2               // ceil(1936/1024)

__global__ void sigma_kernel(const float* __restrict__ xmT,
                             const float* __restrict__ w_sigma,
                             float* __restrict__ out) {
    int bid = blockIdx.x;
    int qb  = bid % NQB;
    int pt  = (bid / NQB) % (P / TP);
    int b   = bid / (NQB * (P / TP));
    int tid = threadIdx.x;
    int p0  = pt * TP;
    int q0  = qb * TQ + tid * 4;

    __shared__ float xp[TP][F + 1];
    __shared__ float sp[KN];

    for (int i = tid; i < TP * F; i += 256) {
        int pp = i / F, f = i % F;
        xp[pp][f] = xmT[((size_t)b * F + f) * P + (p0 + pp)];
    }
    if (tid < KN) sp[tid] = log1pf(expf(w_sigma[tid]));
    __syncthreads();

    if (q0 >= P) return;   // tail q-tile (P%4==0, q0%4==0 so q0..q0+3 all valid)

    float acc[TP][4];
#pragma unroll
    for (int pp = 0; pp < TP; pp++)
#pragma unroll
        for (int j = 0; j < 4; j++) acc[pp][j] = 0.f;

    const float* xq_base = xmT + (size_t)b * F * P + q0;
    for (int f = 0; f < F; f++) {
        float4 xq = *(const float4*)(xq_base + (size_t)f * P);
#pragma unroll
        for (int pp = 0; pp < TP; pp++) {
            float xpv = xp[pp][f];
            acc[pp][0] += xpv * xq.x;
            acc[pp][1] += xpv * xq.y;
            acc[pp][2] += xpv * xq.z;
            acc[pp][3] += xpv * xq.w;
        }
    }

    float* sig = out + MU_OUT_SIZE;
#pragma unroll
    for (int n = 0; n < KN; n++) {
        float s = sp[n];
#pragma unroll
        for (int pp = 0; pp < TP; pp++) {
            size_t o = (((size_t)(b * KN + n)) * P + (p0 + pp)) * P + q0;
            floatx4 v;
            v.x = acc[pp][0] * s;
            v.y = acc[pp][1] * s;
            v.z = acc[pp][2] * s;
            v.w = acc[pp][3] * s;
            __builtin_nontemporal_store(v, reinterpret_cast<floatx4*>(sig + o));
        }
    }
}

// ---------------------------------------------------------------------------
extern "C" void kernel_launch(void* const* d_in, const int* in_sizes, int n_in,
                              void* d_out, int out_size, void* d_ws, size_t ws_size,
                              hipStream_t stream) {
    const float* mu_in   = (const float*)d_in[0];
    const float* w_mu    = (const float*)d_in[1];
    const float* w_sigma = (const float*)d_in[2];
    float* out = (float*)d_out;
    float* xmT = (float*)d_ws;   // needs B*F*P*4 = 1,161,600 bytes

    build_patches<<<(BATCH * F * P + 255) / 256, 256, 0, stream>>>(mu_in, xmT);
    conv_mu<<<(MU_OUT_SIZE + 255) / 256, 256, 0, stream>>>(mu_in, w_mu, out);
    sigma_kernel<<<BATCH * (P / TP) * NQB, 256, 0, stream>>>(xmT, w_sigma, out);
}

// Round 3
// 486.774 us; speedup vs baseline: 1.0485x; 1.0218x over previous
//
#include <hip/hip_runtime.h>
#include <cstddef>
#include <cmath>

// Problem constants (from reference)
#define BATCH 2
#define CIN 3
#define H 48
#define KS 5
#define KN 16
#define OW 44               // H - KS + 1
#define P 1936              // OW*OW patches
#define F 75                // CIN*KS*KS
#define MU_OUT_SIZE (BATCH*KN*P)   // 61952

// Native clang vector type — __builtin_nontemporal_store requires a vector of
// scalar types, not HIP's float4 class.
typedef float floatx4 __attribute__((ext_vector_type(4)));

// ---------------------------------------------------------------------------
// Kernel 1 (fused): grid-fused build_patches + conv_mu (independent jobs,
// one launch). Blocks [0, NB_PATCH) build xmT; blocks [NB_PATCH, ..) do conv.
//
// build:  xmT[b][f][q] = mu_in[b][c][qy+kh][qx+kw], f=(c,kh,kw), q=qy*44+qx
//         (q contiguous so sigma q-loads coalesce; cached stores — we WANT
//          xmT resident in L2 for sigma's 590 MB of re-reads)
// conv:   out[b][n][p] = 5x5 valid conv, weights in LDS, nt store (write-once)
// ---------------------------------------------------------------------------
#define NB_PATCH ((BATCH * F * P + 255) / 256)   // 1135
#define NB_CONV  ((MU_OUT_SIZE + 255) / 256)     // 242

__global__ void prep_kernel(const float* __restrict__ mu_in,
                            const float* __restrict__ w_mu,
                            float* __restrict__ xmT,
                            float* __restrict__ out) {
    if (blockIdx.x < NB_PATCH) {
        int idx = blockIdx.x * 256 + threadIdx.x;
        if (idx >= BATCH * F * P) return;
        int q = idx % P;
        int f = (idx / P) % F;
        int b = idx / (F * P);
        int c  = f / (KS * KS);
        int r  = f % (KS * KS);
        int kh = r / KS, kw = r % KS;
        int qy = q / OW, qx = q % OW;
        xmT[idx] = mu_in[((b * CIN + c) * H + (qy + kh)) * H + (qx + kw)];
    } else {
        __shared__ float wsh[KN * F];
        for (int i = threadIdx.x; i < KN * F; i += 256) wsh[i] = w_mu[i];
        __syncthreads();
        int idx = (blockIdx.x - NB_PATCH) * 256 + threadIdx.x;
        if (idx >= MU_OUT_SIZE) return;
        int p = idx % P;
        int n = (idx / P) % KN;
        int b = idx / (P * KN);
        int py = p / OW, px = p % OW;
        const float* img = mu_in + b * CIN * H * H;
        const float* w   = wsh + n * F;
        float acc = 0.f;
#pragma unroll
        for (int c = 0; c < CIN; c++)
#pragma unroll
            for (int kh = 0; kh < KS; kh++)
#pragma unroll
                for (int kw = 0; kw < KS; kw++)
                    acc += img[(c * H + py + kh) * H + (px + kw)] *
                           w[c * KS * KS + kh * KS + kw];
        __builtin_nontemporal_store(acc, out + idx);
    }
}

// ---------------------------------------------------------------------------
// Kernel 2: sigma[b][n][p][q] = dot_f(xm[p], xm[q]) * softplus(w_sigma[n])
//
// OCCUPANCY CHANGE vs prev round: TP 8 -> 4 doubles the grid to 1936 blocks
// = 7.6 blocks/CU = 30 waves/CU (was 3.8 blocks/CU, 47% occ). nt stores kept
// (write-once stream, bypass L2). __launch_bounds__(256,8) caps VGPR at 64
// (acc is only 16 regs now) so all 30 waves/CU are resident; the extra TLP
// overlaps one block's f-loop (L2-hit loads + FMA) with other blocks' HBM
// store bursts, which 3.8 blocks/CU could not keep saturated.
// Extra xq re-read traffic (590 MB vs 295 MB) is all L2-resident (1.1 MB set).
// ---------------------------------------------------------------------------
#define TP 4
#define TQ 1024
#define NQB 2               // ceil(1936/1024)

__global__ void __launch_bounds__(256, 8)
sigma_kernel(const float* __restrict__ xmT,
             const float* __restrict__ w_sigma,
             float* __restrict__ out) {
    int bid = blockIdx.x;
    int qb  = bid % NQB;
    int pt  = (bid / NQB) % (P / TP);
    int b   = bid / (NQB * (P / TP));
    int tid = threadIdx.x;
    int p0  = pt * TP;
    int q0  = qb * TQ + tid * 4;

    __shared__ float xp[TP][F + 1];
    __shared__ float sp[KN];

    for (int i = tid; i < TP * F; i += 256) {
        int pp = i / F, f = i % F;
        xp[pp][f] = xmT[((size_t)b * F + f) * P + (p0 + pp)];
    }
    if (tid < KN) sp[tid] = log1pf(expf(w_sigma[tid]));
    __syncthreads();

    if (q0 >= P) return;   // tail q-tile (P%4==0, q0%4==0 so q0..q0+3 all valid)

    float acc[TP][4];
#pragma unroll
    for (int pp = 0; pp < TP; pp++)
#pragma unroll
        for (int j = 0; j < 4; j++) acc[pp][j] = 0.f;

    const float* xq_base = xmT + (size_t)b * F * P + q0;
    for (int f = 0; f < F; f++) {
        float4 xq = *(const float4*)(xq_base + (size_t)f * P);
#pragma unroll
        for (int pp = 0; pp < TP; pp++) {
            float xpv = xp[pp][f];
            acc[pp][0] += xpv * xq.x;
            acc[pp][1] += xpv * xq.y;
            acc[pp][2] += xpv * xq.z;
            acc[pp][3] += xpv * xq.w;
        }
    }

    float* sig = out + MU_OUT_SIZE;
#pragma unroll
    for (int n = 0; n < KN; n++) {
        float s = sp[n];
#pragma unroll
        for (int pp = 0; pp < TP; pp++) {
            size_t o = (((size_t)(b * KN + n)) * P + (p0 + pp)) * P + q0;
            floatx4 v;
            v.x = acc[pp][0] * s;
            v.y = acc[pp][1] * s;
            v.z = acc[pp][2] * s;
            v.w = acc[pp][3] * s;
            __builtin_nontemporal_store(v, reinterpret_cast<floatx4*>(sig + o));
        }
    }
}

// ---------------------------------------------------------------------------
extern "C" void kernel_launch(void* const* d_in, const int* in_sizes, int n_in,
                              void* d_out, int out_size, void* d_ws, size_t ws_size,
                              hipStream_t stream) {
    const float* mu_in   = (const float*)d_in[0];
    const float* w_mu    = (const float*)d_in[1];
    const float* w_sigma = (const float*)d_in[2];
    float* out = (float*)d_out;
    float* xmT = (float*)d_ws;   // needs B*F*P*4 = 1,161,600 bytes

    prep_kernel<<<NB_PATCH + NB_CONV, 256, 0, stream>>>(mu_in, w_mu, xmT, out);
    sigma_kernel<<<BATCH * (P / TP) * NQB, 256, 0, stream>>>(xmT, w_sigma, out);
}